// Round 4
// baseline (293.215 us; speedup 1.0000x reference)
//
#include <hip/hip_runtime.h>

// Problem constants (reference: N=16, A=2048, B=2048, H=64)
#define NB 16
#define AQ 2048
#define BKV 2048
#define HD 64

#define MROW 68  // padded f32 row (68*4=272B, 16B-aligned) for merge buffer

typedef float f32x4 __attribute__((ext_vector_type(4)));
typedef short bf16x8 __attribute__((ext_vector_type(8)));
typedef short short4v __attribute__((ext_vector_type(4)));
typedef int int4v __attribute__((ext_vector_type(4)));

__device__ __forceinline__ short f2bf(float f) {
  return __builtin_bit_cast(short, static_cast<__bf16>(f));
}

// Flash attention, swapped-QK^T, in-block split-KV.
// Block = 256 threads = 4 waves. All 4 waves share the SAME 16 q rows; each
// wave processes a disjoint 512-wide quarter of the KV axis with independent
// online-softmax state, then the block merges (m, l, acc) through LDS.
// Grid = N * (A/16) = 2048 blocks -> 8 blocks/CU -> 100% occupancy.
__global__ __launch_bounds__(256, 8) void attn_fwd(
    const float* __restrict__ Q, const float* __restrict__ K,
    const float* __restrict__ V, const int* __restrict__ M,
    float* __restrict__ O) {
  // bijective XCD swizzle: nwg=2048, 256 contiguous wgs per XCD (2 batches/XCD)
  unsigned orig = blockIdx.x;
  unsigned wg = (orig & 7u) * 256u + (orig >> 3);
  int n = (int)(wg >> 7);            // 128 q-tiles per batch
  int q0 = (int)(wg & 127u) * 16;    // block's 16 q rows

  int w = threadIdx.x >> 6;          // wave 0..3 -> KV quarter
  int lane = threadIdx.x & 63;
  int g = lane >> 4;                 // 4-lane-group 0..3
  int c = lane & 15;

  const float* Qn = Q + (size_t)n * AQ * HD;
  const float* Kn = K + (size_t)n * BKV * HD;
  const float* Vn = V + (size_t)n * BKV * HD;
  const int* Mn = M + (size_t)n * BKV;

  // Merge buffer [4 waves][16 q][MROW]; during the loop its first 9216 B are
  // reused as per-wave P staging [16 q][72 bf16]. The overlay REQUIRES the
  // __syncthreads() after the KV loop: merge rows of wave w overlap the
  // P-staging region of wave w+1 (race otherwise — round-2 NaN post-mortem).
  __shared__ __align__(16) float smem[4 * 16 * MROW];  // 17408 B
  __shared__ float Ml[4][2][16];                       // m, l per wave per q
  short* Plds = (short*)smem + (size_t)w * (16 * 72);

  // ---- Q fragments (B operand of swapped QK^T), scale 1/8 folded in.
  // B[k=h][j=q]: lane holds q = q0 + c, h = 32*ks + 8*g + i (8 contiguous f32)
  bf16x8 qb[2];
#pragma unroll
  for (int ks = 0; ks < 2; ++ks) {
    const float* qp = Qn + (size_t)(q0 + c) * HD + 32 * ks + 8 * g;
    f32x4 v0 = *(const f32x4*)qp;
    f32x4 v1 = *(const f32x4*)(qp + 4);
#pragma unroll
    for (int i = 0; i < 4; ++i) {
      qb[ks][i]     = f2bf(v0[i] * 0.125f);
      qb[ks][i + 4] = f2bf(v1[i] * 0.125f);
    }
  }

  // acc[th][r] = O_partial[q = 4g + r][h = 16*th + c]  (unnormalized)
  f32x4 acc[4] = {};
  float m_run = -1e30f;
  float l_run = 0.f;

  const int bbeg = w * (BKV / 4);
  const int bend = bbeg + (BKV / 4);

  for (int b0 = bbeg; b0 < bend; b0 += 64) {
    // ---- S^T = K . Q^T : st[t][r] = S^T[b = b0 + 16t + 4g + r][q = c]
    f32x4 st[4];
#pragma unroll
    for (int t = 0; t < 4; ++t) {
      f32x4 z = {0.f, 0.f, 0.f, 0.f};
#pragma unroll
      for (int ks = 0; ks < 2; ++ks) {
        const float* kp = Kn + (size_t)(b0 + 16 * t + c) * HD + 32 * ks + 8 * g;
        f32x4 k0 = *(const f32x4*)kp;
        f32x4 k1 = *(const f32x4*)(kp + 4);
        bf16x8 ka;
#pragma unroll
        for (int i = 0; i < 4; ++i) {
          ka[i]     = f2bf(k0[i]);
          ka[i + 4] = f2bf(k1[i]);
        }
        z = __builtin_amdgcn_mfma_f32_16x16x32_bf16(ka, qb[ks], z, 0, 0, 0);
      }
      st[t] = z;
    }

    // ---- mask + tile row-max (row q = c; entries spread over t, r, g)
    float p[4][4];
    float mt = -1e30f;
#pragma unroll
    for (int t = 0; t < 4; ++t) {
      int4v mv = *(const int4v*)(Mn + b0 + 16 * t + 4 * g);
#pragma unroll
      for (int r = 0; r < 4; ++r) {
        float s = mv[r] ? -1e30f : st[t][r];
        p[t][r] = s;
        mt = fmaxf(mt, s);
      }
    }
    mt = fmaxf(mt, __shfl_xor(mt, 16));
    mt = fmaxf(mt, __shfl_xor(mt, 32));
    float m_new = fmaxf(m_run, mt);
    float fac = exp2f((m_run - m_new) * 1.44269504f);

    // ---- P = exp(S - m), masked entries exactly 0
    float rs = 0.f;
#pragma unroll
    for (int t = 0; t < 4; ++t) {
#pragma unroll
      for (int r = 0; r < 4; ++r) {
        float s = p[t][r];
        float e = (s <= -1e29f) ? 0.f : exp2f((s - m_new) * 1.44269504f);
        p[t][r] = e;
        rs += e;
      }
    }
    rs += __shfl_xor(rs, 16);
    rs += __shfl_xor(rs, 32);
    l_run = l_run * fac + rs;
    m_run = m_new;

    // ---- rescale accumulator rows (row q = 4g + r; factor lives in lane 4g+r)
#pragma unroll
    for (int r = 0; r < 4; ++r) {
      float fr = __shfl(fac, 4 * g + r);
#pragma unroll
      for (int th = 0; th < 4; ++th) acc[th][r] *= fr;
    }

    // ---- P -> wave-private LDS (layout P[q][b], stride 72 shorts)
#pragma unroll
    for (int t = 0; t < 4; ++t) {
      short4v pk;
#pragma unroll
      for (int r = 0; r < 4; ++r) pk[r] = f2bf(p[t][r]);
      *(short4v*)(Plds + c * 72 + 16 * t + 4 * g) = pk;
    }

    // ---- PV: A = P[q=c][b = 32ks + 8g + i], B = V[b][h = 16th + c]
    bf16x8 pa[2];
#pragma unroll
    for (int ks = 0; ks < 2; ++ks)
      pa[ks] = *(const bf16x8*)(Plds + c * 72 + 32 * ks + 8 * g);
#pragma unroll
    for (int th = 0; th < 4; ++th) {
#pragma unroll
      for (int ks = 0; ks < 2; ++ks) {
        const float* vp = Vn + (size_t)(b0 + 32 * ks + 8 * g) * HD + 16 * th + c;
        bf16x8 vb;
#pragma unroll
        for (int i = 0; i < 8; ++i) vb[i] = f2bf(vp[(size_t)i * HD]);
        acc[th] = __builtin_amdgcn_mfma_f32_16x16x32_bf16(pa[ks], vb, acc[th], 0, 0, 0);
      }
    }
  }

  // ---- all waves must be done with their P-staging reads before the merge
  // buffer (which overlaps it) is written. THIS BARRIER IS LOAD-BEARING.
  __syncthreads();

  // ---- publish per-wave partials (m, l, unnormalized acc) to LDS
  if (g == 0) {
    Ml[w][0][c] = m_run;   // q = c (after xor-16/32 reduce, all g identical)
    Ml[w][1][c] = l_run;
  }
#pragma unroll
  for (int r = 0; r < 4; ++r) {
#pragma unroll
    for (int th = 0; th < 4; ++th) {
      smem[(size_t)(w * 16 + 4 * g + r) * MROW + 16 * th + c] = acc[th][r];
    }
  }
  __syncthreads();

  // ---- merge 4 wave-partials; 256 threads cover 16 q x 16 h-quads
  {
    int tid = threadIdx.x;
    int q = tid >> 4;            // 0..15
    int hb = (tid & 15) * 4;     // 0,4,...,60
    float m0 = Ml[0][0][q], m1 = Ml[1][0][q];
    float m2 = Ml[2][0][q], m3 = Ml[3][0][q];
    float mmax = fmaxf(fmaxf(m0, m1), fmaxf(m2, m3));
    float lsum = 0.f;
    f32x4 o = {0.f, 0.f, 0.f, 0.f};
#pragma unroll
    for (int ww = 0; ww < 4; ++ww) {
      float f = exp2f((Ml[ww][0][q] - mmax) * 1.44269504f);
      lsum += f * Ml[ww][1][q];
      f32x4 a = *(const f32x4*)(smem + (size_t)(ww * 16 + q) * MROW + hb);
#pragma unroll
      for (int i = 0; i < 4; ++i) o[i] += f * a[i];
    }
    float inv = 1.0f / lsum;
    f32x4 res;
#pragma unroll
    for (int i = 0; i < 4; ++i) res[i] = o[i] * inv;
    *(f32x4*)(O + ((size_t)n * AQ + q0 + q) * HD + hb) = res;
  }
}

extern "C" void kernel_launch(void* const* d_in, const int* in_sizes, int n_in,
                              void* d_out, int out_size, void* d_ws, size_t ws_size,
                              hipStream_t stream) {
  const float* q = (const float*)d_in[0];
  const float* k = (const float*)d_in[1];
  const float* v = (const float*)d_in[2];
  const int* m = (const int*)d_in[3];
  float* o = (float*)d_out;
  attn_fwd<<<dim3(NB * (AQ / 16)), dim3(256), 0, stream>>>(q, k, v, m, o);
}

// Round 5
// 237.989 us; speedup vs baseline: 1.2321x; 1.2321x over previous
//
#include <hip/hip_runtime.h>

// Problem constants (reference: N=16, A=2048, B=2048, H=64)
#define NB 16
#define AQ 2048
#define BKV 2048
#define HD 64

#define MROW 68  // padded f32 row (68*4=272B, 16B-aligned) for merge buffer

typedef float f32x4 __attribute__((ext_vector_type(4)));
typedef short bf16x8 __attribute__((ext_vector_type(8)));
typedef short short4v __attribute__((ext_vector_type(4)));
typedef int int4v __attribute__((ext_vector_type(4)));

__device__ __forceinline__ short f2bf(float f) {
  return __builtin_bit_cast(short, static_cast<__bf16>(f));
}

// ---------------- prepass 1: K f32 [n][b][h] -> bf16 [n][b][h] ----------------
__global__ __launch_bounds__(256) void conv_k(const float* __restrict__ K,
                                              short* __restrict__ Kb) {
  size_t base = ((size_t)blockIdx.x * 256 + threadIdx.x) * 8;
  f32x4 a = *(const f32x4*)(K + base);
  f32x4 b = *(const f32x4*)(K + base + 4);
  bf16x8 o;
#pragma unroll
  for (int i = 0; i < 4; ++i) {
    o[i] = f2bf(a[i]);
    o[i + 4] = f2bf(b[i]);
  }
  *(bf16x8*)(Kb + base) = o;
}

// ------------- prepass 2: V f32 [n][b][h] -> Vt bf16 [n][h][b] ---------------
// 64(b) x 64(h) tiles via LDS. Grid = NB * (BKV/64).
__global__ __launch_bounds__(256) void conv_vt(const float* __restrict__ V,
                                               short* __restrict__ Vt) {
  int n = blockIdx.x >> 5;
  int b0 = (blockIdx.x & 31) * 64;
  int t = threadIdx.x;
  __shared__ short tile[64][68];  // bf16, pad to 68
  int rb = t >> 4;        // 0..15
  int hc = (t & 15) * 4;  // 0,4,..,60
#pragma unroll
  for (int j = 0; j < 4; ++j) {
    int r = rb + 16 * j;
    f32x4 v = *(const f32x4*)(V + ((size_t)n * BKV + b0 + r) * HD + hc);
#pragma unroll
    for (int i = 0; i < 4; ++i) tile[r][hc + i] = f2bf(v[i]);
  }
  __syncthreads();
  int hr = t >> 2;        // 0..63
  int bb = (t & 3) * 16;  // 0,16,32,48
  bf16x8 o0, o1;
#pragma unroll
  for (int j = 0; j < 8; ++j) {
    o0[j] = tile[bb + j][hr];
    o1[j] = tile[bb + 8 + j][hr];
  }
  short* dst = Vt + ((size_t)n * HD + hr) * BKV + b0 + bb;
  *(bf16x8*)dst = o0;
  *(bf16x8*)(dst + 8) = o1;
}

// ---------------------------- main flash kernel ------------------------------
// Swapped-QK^T, in-block split-KV. Block = 4 waves; all share 16 q rows; each
// wave owns a 512-wide KV quarter with private online-softmax state; block
// merges (m, l, acc) through LDS at the end. Grid = N*A/16 = 2048 blocks.
// PRE=1: K/V fragments are direct bf16x8 loads from prepacked Kb / Vt.
// PRE=0: round-4 verified fallback (f32 loads + inline convert).
template <int PRE>
__global__ __launch_bounds__(256, 8) void attn_fwd(
    const float* __restrict__ Q, const float* __restrict__ K,
    const float* __restrict__ V, const int* __restrict__ M,
    const short* __restrict__ Kb, const short* __restrict__ Vt,
    float* __restrict__ O) {
  // bijective XCD swizzle: nwg=2048, 256 contiguous wgs per XCD (2 batches/XCD)
  unsigned orig = blockIdx.x;
  unsigned wg = (orig & 7u) * 256u + (orig >> 3);
  int n = (int)(wg >> 7);
  int q0 = (int)(wg & 127u) * 16;

  int w = threadIdx.x >> 6;
  int lane = threadIdx.x & 63;
  int g = lane >> 4;
  int c = lane & 15;

  const float* Qn = Q + (size_t)n * AQ * HD;
  const float* Kn = K + (size_t)n * BKV * HD;
  const float* Vn = V + (size_t)n * BKV * HD;
  const short* Kbn = Kb + (size_t)n * BKV * HD;
  const short* Vtn = Vt + (size_t)n * HD * BKV;
  const int* Mn = M + (size_t)n * BKV;

  // Merge buffer overlays per-wave P staging; the post-loop __syncthreads()
  // is LOAD-BEARING (round-2 NaN post-mortem: cross-wave overlay race).
  __shared__ __align__(16) float smem[4 * 16 * MROW];  // 17408 B
  __shared__ float Ml[4][2][16];
  short* Plds = (short*)smem + (size_t)w * (16 * 72);

  // Q fragments (B operand), scale 1/8 folded in.
  bf16x8 qb[2];
#pragma unroll
  for (int ks = 0; ks < 2; ++ks) {
    const float* qp = Qn + (size_t)(q0 + c) * HD + 32 * ks + 8 * g;
    f32x4 v0 = *(const f32x4*)qp;
    f32x4 v1 = *(const f32x4*)(qp + 4);
#pragma unroll
    for (int i = 0; i < 4; ++i) {
      qb[ks][i] = f2bf(v0[i] * 0.125f);
      qb[ks][i + 4] = f2bf(v1[i] * 0.125f);
    }
  }

  f32x4 acc[4] = {};
  float m_run = -1e30f;
  float l_run = 0.f;

  const int bbeg = w * (BKV / 4);
  const int bend = bbeg + (BKV / 4);

  for (int b0 = bbeg; b0 < bend; b0 += 64) {
    // ---- S^T = K . Q^T : st[t][r] = S^T[b = b0 + 16t + 4g + r][q = c]
    f32x4 st[4];
#pragma unroll
    for (int t = 0; t < 4; ++t) {
      f32x4 z = {0.f, 0.f, 0.f, 0.f};
#pragma unroll
      for (int ks = 0; ks < 2; ++ks) {
        bf16x8 ka;
        if constexpr (PRE) {
          ka = *(const bf16x8*)(Kbn + (size_t)(b0 + 16 * t + c) * HD + 32 * ks + 8 * g);
        } else {
          const float* kp = Kn + (size_t)(b0 + 16 * t + c) * HD + 32 * ks + 8 * g;
          f32x4 k0 = *(const f32x4*)kp;
          f32x4 k1 = *(const f32x4*)(kp + 4);
#pragma unroll
          for (int i = 0; i < 4; ++i) {
            ka[i] = f2bf(k0[i]);
            ka[i + 4] = f2bf(k1[i]);
          }
        }
        z = __builtin_amdgcn_mfma_f32_16x16x32_bf16(ka, qb[ks], z, 0, 0, 0);
      }
      st[t] = z;
    }

    // ---- mask + tile row-max
    float p[4][4];
    float mt = -1e30f;
#pragma unroll
    for (int t = 0; t < 4; ++t) {
      int4v mv = *(const int4v*)(Mn + b0 + 16 * t + 4 * g);
#pragma unroll
      for (int r = 0; r < 4; ++r) {
        float s = mv[r] ? -1e30f : st[t][r];
        p[t][r] = s;
        mt = fmaxf(mt, s);
      }
    }
    mt = fmaxf(mt, __shfl_xor(mt, 16));
    mt = fmaxf(mt, __shfl_xor(mt, 32));
    float m_new = fmaxf(m_run, mt);
    float fac = exp2f((m_run - m_new) * 1.44269504f);

    // ---- P = exp(S - m), masked entries exactly 0
    float rs = 0.f;
#pragma unroll
    for (int t = 0; t < 4; ++t) {
#pragma unroll
      for (int r = 0; r < 4; ++r) {
        float s = p[t][r];
        float e = (s <= -1e29f) ? 0.f : exp2f((s - m_new) * 1.44269504f);
        p[t][r] = e;
        rs += e;
      }
    }
    rs += __shfl_xor(rs, 16);
    rs += __shfl_xor(rs, 32);
    l_run = l_run * fac + rs;
    m_run = m_new;

    // ---- rescale accumulator rows
#pragma unroll
    for (int r = 0; r < 4; ++r) {
      float fr = __shfl(fac, 4 * g + r);
#pragma unroll
      for (int th = 0; th < 4; ++th) acc[th][r] *= fr;
    }

    // ---- P -> wave-private LDS (layout P[q][b], stride 72 shorts)
#pragma unroll
    for (int t = 0; t < 4; ++t) {
      short4v pk;
#pragma unroll
      for (int r = 0; r < 4; ++r) pk[r] = f2bf(p[t][r]);
      *(short4v*)(Plds + c * 72 + 16 * t + 4 * g) = pk;
    }

    // ---- PV: A = P[q=c][b-frag], B = V[b][h = 16th + c]
    bf16x8 pa[2];
#pragma unroll
    for (int ks = 0; ks < 2; ++ks)
      pa[ks] = *(const bf16x8*)(Plds + c * 72 + 32 * ks + 8 * g);
#pragma unroll
    for (int th = 0; th < 4; ++th) {
#pragma unroll
      for (int ks = 0; ks < 2; ++ks) {
        bf16x8 vb;
        if constexpr (PRE) {
          vb = *(const bf16x8*)(Vtn + (size_t)(16 * th + c) * BKV + b0 + 32 * ks + 8 * g);
        } else {
          const float* vp = Vn + (size_t)(b0 + 32 * ks + 8 * g) * HD + 16 * th + c;
#pragma unroll
          for (int i = 0; i < 8; ++i) vb[i] = f2bf(vp[(size_t)i * HD]);
        }
        acc[th] = __builtin_amdgcn_mfma_f32_16x16x32_bf16(pa[ks], vb, acc[th], 0, 0, 0);
      }
    }
  }

  // ---- LOAD-BEARING barrier: P-staging reads must finish before the merge
  // buffer (which overlaps other waves' staging) is written.
  __syncthreads();

  if (g == 0) {
    Ml[w][0][c] = m_run;
    Ml[w][1][c] = l_run;
  }
#pragma unroll
  for (int r = 0; r < 4; ++r) {
#pragma unroll
    for (int th = 0; th < 4; ++th) {
      smem[(size_t)(w * 16 + 4 * g + r) * MROW + 16 * th + c] = acc[th][r];
    }
  }
  __syncthreads();

  // ---- merge 4 wave-partials; 256 threads cover 16 q x 16 h-quads
  {
    int tid = threadIdx.x;
    int q = tid >> 4;
    int hb = (tid & 15) * 4;
    float m0 = Ml[0][0][q], m1 = Ml[1][0][q];
    float m2 = Ml[2][0][q], m3 = Ml[3][0][q];
    float mmax = fmaxf(fmaxf(m0, m1), fmaxf(m2, m3));
    float lsum = 0.f;
    f32x4 o = {0.f, 0.f, 0.f, 0.f};
#pragma unroll
    for (int ww = 0; ww < 4; ++ww) {
      float f = exp2f((Ml[ww][0][q] - mmax) * 1.44269504f);
      lsum += f * Ml[ww][1][q];
      f32x4 a = *(const f32x4*)(smem + (size_t)(ww * 16 + q) * MROW + hb);
#pragma unroll
      for (int i = 0; i < 4; ++i) o[i] += f * a[i];
    }
    float inv = 1.0f / lsum;
    f32x4 res;
#pragma unroll
    for (int i = 0; i < 4; ++i) res[i] = o[i] * inv;
    *(f32x4*)(O + ((size_t)n * AQ + q0 + q) * HD + hb) = res;
  }
}

extern "C" void kernel_launch(void* const* d_in, const int* in_sizes, int n_in,
                              void* d_out, int out_size, void* d_ws, size_t ws_size,
                              hipStream_t stream) {
  const float* q = (const float*)d_in[0];
  const float* k = (const float*)d_in[1];
  const float* v = (const float*)d_in[2];
  const int* m = (const int*)d_in[3];
  float* o = (float*)d_out;

  const size_t kv_elems = (size_t)NB * BKV * HD;  // 2,097,152
  const size_t need = kv_elems * 2 * sizeof(short);  // Kb + Vt = 8 MB

  if (ws_size >= need) {
    short* kb = (short*)d_ws;
    short* vt = kb + kv_elems;
    conv_k<<<dim3((unsigned)(kv_elems / 8 / 256)), dim3(256), 0, stream>>>(k, kb);
    conv_vt<<<dim3(NB * (BKV / 64)), dim3(256), 0, stream>>>(v, vt);
    attn_fwd<1><<<dim3(NB * (AQ / 16)), dim3(256), 0, stream>>>(q, k, v, m, kb, vt, o);
  } else {
    attn_fwd<0><<<dim3(NB * (AQ / 16)), dim3(256), 0, stream>>>(q, k, v, m, nullptr, nullptr, o);
  }
}

// Round 6
// 202.696 us; speedup vs baseline: 1.4466x; 1.1741x over previous
//
#include <hip/hip_runtime.h>

// Problem constants (reference: N=16, A=2048, B=2048, H=64)
#define NB 16
#define AQ 2048
#define BKV 2048
#define HD 64

#define MROW 68  // padded f32 row (68*4=272B, 16B-aligned) for merge buffer

typedef float f32x4 __attribute__((ext_vector_type(4)));
typedef short bf16x8 __attribute__((ext_vector_type(8)));
typedef short short4v __attribute__((ext_vector_type(4)));
typedef int int4v __attribute__((ext_vector_type(4)));

__device__ __forceinline__ short f2bf(float f) {
  return __builtin_bit_cast(short, static_cast<__bf16>(f));
}

// -------------------- fused prepass (single launch) --------------------------
// blocks [0, 1024):   K f32 [n][b][h] -> Kb bf16 [n][b][h]   (2048 elems/blk)
// blocks [1024, 1536): V f32 [n][b][h] -> Vt bf16 [n][h][b]  (64x64 LDS tile)
__global__ __launch_bounds__(256) void prepack(const float* __restrict__ K,
                                               const float* __restrict__ V,
                                               short* __restrict__ Kb,
                                               short* __restrict__ Vt) {
  if (blockIdx.x < 1024) {
    size_t base = ((size_t)blockIdx.x * 256 + threadIdx.x) * 8;
    f32x4 a = *(const f32x4*)(K + base);
    f32x4 b = *(const f32x4*)(K + base + 4);
    bf16x8 o;
#pragma unroll
    for (int i = 0; i < 4; ++i) {
      o[i] = f2bf(a[i]);
      o[i + 4] = f2bf(b[i]);
    }
    *(bf16x8*)(Kb + base) = o;
  } else {
    unsigned vb = blockIdx.x - 1024;
    int n = vb >> 5;
    int b0 = (vb & 31) * 64;
    int t = threadIdx.x;
    __shared__ short tile[64][68];  // bf16, pad to 68
    int rb = t >> 4;
    int hc = (t & 15) * 4;
#pragma unroll
    for (int j = 0; j < 4; ++j) {
      int r = rb + 16 * j;
      f32x4 v = *(const f32x4*)(V + ((size_t)n * BKV + b0 + r) * HD + hc);
#pragma unroll
      for (int i = 0; i < 4; ++i) tile[r][hc + i] = f2bf(v[i]);
    }
    __syncthreads();
    int hr = t >> 2;
    int bb = (t & 3) * 16;
    bf16x8 o0, o1;
#pragma unroll
    for (int j = 0; j < 8; ++j) {
      o0[j] = tile[bb + j][hr];
      o1[j] = tile[bb + 8 + j][hr];
    }
    short* dst = Vt + ((size_t)n * HD + hr) * BKV + b0 + bb;
    *(bf16x8*)dst = o0;
    *(bf16x8*)(dst + 8) = o1;
  }
}

// ---------------------------- main flash kernel ------------------------------
// Swapped-QK^T, in-block split-KV. Block = 4 waves; all share 16 q rows; each
// wave owns a 512-wide KV quarter with private online-softmax state; block
// merges (m, l, acc) through LDS at the end. Grid = N*A/16 = 2048 blocks.
// __launch_bounds__(256, 4): VGPR cap 128. DO NOT raise min-waves to 8 —
// that caps VGPR at 64 and spills acc to scratch (round-5 post-mortem:
// WRITE_SIZE ballooned to 114-198 MB, dur stuck at ~172 us).
template <int PRE>
__global__ __launch_bounds__(256, 4) void attn_fwd(
    const float* __restrict__ Q, const float* __restrict__ K,
    const float* __restrict__ V, const int* __restrict__ M,
    const short* __restrict__ Kb, const short* __restrict__ Vt,
    float* __restrict__ O) {
  // bijective XCD swizzle: nwg=2048, 256 contiguous wgs per XCD (2 batches/XCD)
  unsigned orig = blockIdx.x;
  unsigned wg = (orig & 7u) * 256u + (orig >> 3);
  int n = (int)(wg >> 7);
  int q0 = (int)(wg & 127u) * 16;

  int w = threadIdx.x >> 6;
  int lane = threadIdx.x & 63;
  int g = lane >> 4;
  int c = lane & 15;

  const float* Qn = Q + (size_t)n * AQ * HD;
  const float* Kn = K + (size_t)n * BKV * HD;
  const float* Vn = V + (size_t)n * BKV * HD;
  const short* Kbn = Kb + (size_t)n * BKV * HD;
  const short* Vtn = Vt + (size_t)n * HD * BKV;
  const int* Mn = M + (size_t)n * BKV;

  // Merge buffer overlays per-wave P staging; the post-loop __syncthreads()
  // is LOAD-BEARING (round-2 NaN post-mortem: cross-wave overlay race).
  __shared__ __align__(16) float smem[4 * 16 * MROW];  // 17408 B
  __shared__ float Ml[4][2][16];
  short* Plds = (short*)smem + (size_t)w * (16 * 72);

  // Q fragments (B operand), scale 1/8 folded in.
  bf16x8 qb[2];
#pragma unroll
  for (int ks = 0; ks < 2; ++ks) {
    const float* qp = Qn + (size_t)(q0 + c) * HD + 32 * ks + 8 * g;
    f32x4 v0 = *(const f32x4*)qp;
    f32x4 v1 = *(const f32x4*)(qp + 4);
#pragma unroll
    for (int i = 0; i < 4; ++i) {
      qb[ks][i] = f2bf(v0[i] * 0.125f);
      qb[ks][i + 4] = f2bf(v1[i] * 0.125f);
    }
  }

  f32x4 acc[4] = {};
  float m_run = -1e30f;
  float l_run = 0.f;

  const int bbeg = w * (BKV / 4);
  const int bend = bbeg + (BKV / 4);

  for (int b0 = bbeg; b0 < bend; b0 += 64) {
    // ---- S^T = K . Q^T : st[t][r] = S^T[b = b0 + 16t + 4g + r][q = c]
    f32x4 st[4];
#pragma unroll
    for (int t = 0; t < 4; ++t) {
      f32x4 z = {0.f, 0.f, 0.f, 0.f};
#pragma unroll
      for (int ks = 0; ks < 2; ++ks) {
        bf16x8 ka;
        if constexpr (PRE) {
          ka = *(const bf16x8*)(Kbn + (size_t)(b0 + 16 * t + c) * HD + 32 * ks + 8 * g);
        } else {
          const float* kp = Kn + (size_t)(b0 + 16 * t + c) * HD + 32 * ks + 8 * g;
          f32x4 k0 = *(const f32x4*)kp;
          f32x4 k1 = *(const f32x4*)(kp + 4);
#pragma unroll
          for (int i = 0; i < 4; ++i) {
            ka[i] = f2bf(k0[i]);
            ka[i + 4] = f2bf(k1[i]);
          }
        }
        z = __builtin_amdgcn_mfma_f32_16x16x32_bf16(ka, qb[ks], z, 0, 0, 0);
      }
      st[t] = z;
    }

    // ---- mask + tile row-max (in place in st; saves 16 VGPRs vs separate p)
    float mt = -1e30f;
#pragma unroll
    for (int t = 0; t < 4; ++t) {
      int4v mv = *(const int4v*)(Mn + b0 + 16 * t + 4 * g);
#pragma unroll
      for (int r = 0; r < 4; ++r) {
        float s = mv[r] ? -1e30f : st[t][r];
        st[t][r] = s;
        mt = fmaxf(mt, s);
      }
    }
    mt = fmaxf(mt, __shfl_xor(mt, 16));
    mt = fmaxf(mt, __shfl_xor(mt, 32));
    float m_new = fmaxf(m_run, mt);
    float fac = exp2f((m_run - m_new) * 1.44269504f);

    // ---- P = exp(S - m) in place, masked entries exactly 0
    float rs = 0.f;
#pragma unroll
    for (int t = 0; t < 4; ++t) {
#pragma unroll
      for (int r = 0; r < 4; ++r) {
        float s = st[t][r];
        float e = (s <= -1e29f) ? 0.f : exp2f((s - m_new) * 1.44269504f);
        st[t][r] = e;
        rs += e;
      }
    }
    rs += __shfl_xor(rs, 16);
    rs += __shfl_xor(rs, 32);
    l_run = l_run * fac + rs;
    m_run = m_new;

    // ---- rescale accumulator rows (row q = 4g + r; factor lives in lane 4g+r)
#pragma unroll
    for (int r = 0; r < 4; ++r) {
      float fr = __shfl(fac, 4 * g + r);
#pragma unroll
      for (int th = 0; th < 4; ++th) acc[th][r] *= fr;
    }

    // ---- P -> wave-private LDS (layout P[q][b], stride 72 shorts)
#pragma unroll
    for (int t = 0; t < 4; ++t) {
      short4v pk;
#pragma unroll
      for (int r = 0; r < 4; ++r) pk[r] = f2bf(st[t][r]);
      *(short4v*)(Plds + c * 72 + 16 * t + 4 * g) = pk;
    }

    // ---- PV: A = P[q=c][b-frag], B = V[b][h = 16th + c]
    bf16x8 pa[2];
#pragma unroll
    for (int ks = 0; ks < 2; ++ks)
      pa[ks] = *(const bf16x8*)(Plds + c * 72 + 32 * ks + 8 * g);
#pragma unroll
    for (int th = 0; th < 4; ++th) {
#pragma unroll
      for (int ks = 0; ks < 2; ++ks) {
        bf16x8 vb;
        if constexpr (PRE) {
          vb = *(const bf16x8*)(Vtn + (size_t)(16 * th + c) * BKV + b0 + 32 * ks + 8 * g);
        } else {
          const float* vp = Vn + (size_t)(b0 + 32 * ks + 8 * g) * HD + 16 * th + c;
#pragma unroll
          for (int i = 0; i < 8; ++i) vb[i] = f2bf(vp[(size_t)i * HD]);
        }
        acc[th] = __builtin_amdgcn_mfma_f32_16x16x32_bf16(pa[ks], vb, acc[th], 0, 0, 0);
      }
    }
  }

  // ---- LOAD-BEARING barrier: P-staging reads must finish before the merge
  // buffer (which overlaps other waves' staging) is written.
  __syncthreads();

  if (g == 0) {
    Ml[w][0][c] = m_run;
    Ml[w][1][c] = l_run;
  }
#pragma unroll
  for (int r = 0; r < 4; ++r) {
#pragma unroll
    for (int th = 0; th < 4; ++th) {
      smem[(size_t)(w * 16 + 4 * g + r) * MROW + 16 * th + c] = acc[th][r];
    }
  }
  __syncthreads();

  // ---- merge 4 wave-partials; 256 threads cover 16 q x 16 h-quads
  {
    int tid = threadIdx.x;
    int q = tid >> 4;
    int hb = (tid & 15) * 4;
    float m0 = Ml[0][0][q], m1 = Ml[1][0][q];
    float m2 = Ml[2][0][q], m3 = Ml[3][0][q];
    float mmax = fmaxf(fmaxf(m0, m1), fmaxf(m2, m3));
    float lsum = 0.f;
    f32x4 o = {0.f, 0.f, 0.f, 0.f};
#pragma unroll
    for (int ww = 0; ww < 4; ++ww) {
      float f = exp2f((Ml[ww][0][q] - mmax) * 1.44269504f);
      lsum += f * Ml[ww][1][q];
      f32x4 a = *(const f32x4*)(smem + (size_t)(ww * 16 + q) * MROW + hb);
#pragma unroll
      for (int i = 0; i < 4; ++i) o[i] += f * a[i];
    }
    float inv = 1.0f / lsum;
    f32x4 res;
#pragma unroll
    for (int i = 0; i < 4; ++i) res[i] = o[i] * inv;
    *(f32x4*)(O + ((size_t)n * AQ + q0 + q) * HD + hb) = res;
  }
}

extern "C" void kernel_launch(void* const* d_in, const int* in_sizes, int n_in,
                              void* d_out, int out_size, void* d_ws, size_t ws_size,
                              hipStream_t stream) {
  const float* q = (const float*)d_in[0];
  const float* k = (const float*)d_in[1];
  const float* v = (const float*)d_in[2];
  const int* m = (const int*)d_in[3];
  float* o = (float*)d_out;

  const size_t kv_elems = (size_t)NB * BKV * HD;     // 2,097,152
  const size_t need = kv_elems * 2 * sizeof(short);  // Kb + Vt = 8 MB

  if (ws_size >= need) {
    short* kb = (short*)d_ws;
    short* vt = kb + kv_elems;
    prepack<<<dim3(1536), dim3(256), 0, stream>>>(k, v, kb, vt);
    attn_fwd<1><<<dim3(NB * (AQ / 16)), dim3(256), 0, stream>>>(q, k, v, m, kb, vt, o);
  } else {
    attn_fwd<0><<<dim3(NB * (AQ / 16)), dim3(256), 0, stream>>>(q, k, v, m, nullptr, nullptr, o);
  }
}